// Round 13
// baseline (491.548 us; speedup 1.0000x reference)
//
#include <hip/hip_runtime.h>

// Problem constants (B,N,T,F,H,R) = (32,1024,32,5,64,5)
constexpr int Bc = 32, Nc = 1024, Tc = 32, Fc = 5, Hc = 64;
constexpr int BNc = Bc * Nc;   // 32768 sequences

#define DEVFN __device__ __forceinline__

typedef _Float16 f16x8 __attribute__((ext_vector_type(8)));
typedef _Float16 f16x4 __attribute__((ext_vector_type(4)));
typedef float    f32x16 __attribute__((ext_vector_type(16)));

DEVFN float fast_rcp(float x) { return __builtin_amdgcn_rcpf(x); }
DEVFN float tanh_fast(float x) { return 1.f - 2.f * fast_rcp(__expf(2.f * x) + 1.f); }

#if __has_builtin(__builtin_amdgcn_exp2f)
DEVFN float exp2_fast(float x) { return __builtin_amdgcn_exp2f(x); }
#else
DEVFN float exp2_fast(float x) { return exp2f(x); }
#endif

// ------------- Fused kernel: LSTM+attention (blocks 0..1023) ----------------
//                + edge-coefficient phase (blocks 1024..2047)
// R13: pure-occupancy probe. launch_bounds(128,4) requests 4 waves/EU
// (8 blocks/CU); coefq phase restructured into two 16-row halves so the LDS
// overlay drops to 18944 B (8 blocks/CU by LDS). LSTM body = R9 verbatim.
__global__ __launch_bounds__(128, 4) void lstm_coefq_kernel(
    const float* __restrict__ x,      // [BN, T, F]
    const float* __restrict__ Wih,    // [4H, F]
    const float* __restrict__ Whh,    // [4H, H]
    const float* __restrict__ bih,    // [4H]
    const float* __restrict__ bhh,    // [4H]
    const float* __restrict__ attn_w, // [H]
    const float* __restrict__ attn_b, // [1]
    const float* __restrict__ A,      // [N, N, R]
    const float* __restrict__ gnn_w,  // [R]
    const float* __restrict__ gnn_b,  // [1]
    _Float16* __restrict__ E16,       // [B*N, H] fp16 row-major
    _Float16* __restrict__ ET,        // [B][H][N] fp16 transposed
    _Float16* __restrict__ coefQH,    // [N/4][N][4] fp16
    float* __restrict__ degP)         // [32][N] partial counts
{
    // LDS overlay: lstm 18944 B (xs 10496 | hb 8192 | ap 256);
    // coefq 10368 B (as 16x162 floats). Max = 18944 B -> 8 blocks/CU.
    __shared__ __align__(16) char smem[18944];

    const int tid  = threadIdx.x;

    if (blockIdx.x >= 1024) {
        // =================== coefq phase (128 threads) ======================
        // Two 16-row halves; thread = (i_loc = tid>>3, qg = tid&7) handles one
        // j-quad of one row per half. Degree via shfl over the 8 qg lanes.
        constexpr int CP = 162;                 // float pitch
        float* as = (float*)smem;               // [16][162]
        const int cb = blockIdx.x - 1024;
        const int it = cb >> 5, jt = cb & 31;
        const int i_loc = tid >> 3, qg = tid & 7;

        float gw[5];
        #pragma unroll
        for (int f = 0; f < 5; ++f) gw[f] = gnn_w[f];
        const float gb = gnn_b[0];

        #pragma unroll 1
        for (int half = 0; half < 2; ++half) {
            const float* src = A + ((size_t)(it * 32 + half * 16) * 1024 + jt * 32) * 5;
            // stage 16 rows x 160 floats (coalesced float2): 1280 lds / 128 thr
            #pragma unroll
            for (int k = 0; k < 10; ++k) {
                int idx = tid + k * 128;
                int row = idx / 80, c2 = idx - row * 80;
                *(float2*)&as[row * CP + c2 * 2] =
                    *(const float2*)(src + (size_t)row * 5120 + c2 * 2);
            }
            __syncthreads();

            float cf[4]; float cnt = 0.f;
            #pragma unroll
            for (int q = 0; q < 4; ++q) {
                const float* ap_ = &as[i_loc * CP + (qg * 4 + q) * 5];
                float s = 0.f, d = gb;
                #pragma unroll
                for (int f = 0; f < 5; ++f) { float vv = ap_[f]; s += vv; d = fmaf(vv, gw[f], d); }
                cf[q] = (s > 0.f) ? (d >= 0.f ? d : 0.2f * d) : 0.f;
                cnt += (s > 0.f) ? 1.f : 0.f;
            }
            ((f16x4*)coefQH)[(size_t)(jt * 8 + qg) * 1024 + it * 32 + half * 16 + i_loc] =
                f16x4{(_Float16)cf[0], (_Float16)cf[1], (_Float16)cf[2], (_Float16)cf[3]};

            cnt += __shfl_xor(cnt, 1);
            cnt += __shfl_xor(cnt, 2);
            cnt += __shfl_xor(cnt, 4);
            if (qg == 0)
                degP[jt * 1024 + it * 32 + half * 16 + i_loc] = cnt;
            __syncthreads();    // as[] fully consumed before next half stages
        }
        return;
    }

    // ======================= LSTM + attention phase (R9) ====================
    constexpr int XP = 164;                     // x pitch (halves)
    _Float16* xs  = (_Float16*)smem;            // [32][164]; aliased w/ es
    _Float16* hbp = (_Float16*)(smem + 10496);  // [2][32*64]
    float*    ap  = (float*)(smem + 10496 + 8192); // [2][32]
    float*    es  = (float*)xs;                 // [32][65] epilogue bounce

    const int w    = tid >> 6;                  // wave id (0,1)
    const int lane = tid & 63;
    const int m    = lane & 31;                 // seq column
    const int hi   = lane >> 5;

    // ---- stage x (fp32 -> fp16 LDS) ----
    const float* xg = x + (size_t)blockIdx.x * 32 * Tc * Fc;
    for (int i = tid; i < 32 * 160; i += 128) {
        int mm = i / 160, o = i - mm * 160;
        xs[mm * XP + o] = (_Float16)xg[i];
    }
    // zero h buffer 0
    for (int i = tid; i < 1024; i += 128) ((uint*)hbp)[i] = 0u;

    // per-gate exp2 folding scales (gate order i,f,g,o)
    constexpr float L2E = 1.4426950408889634f;
    const float gsc[4] = {-L2E, -L2E, 2.f * L2E, -L2E};

    // ---- preload A fragments: af[g][kt], jt = 2g+w, row j = 32*jt + m ----
    f16x8 af[4][5];
    #pragma unroll
    for (int g = 0; g < 4; ++g) {
        const int j = 32 * (2 * g + w) + m;     // = 64g + 32w + m
        const float sc = gsc[g];
        #pragma unroll
        for (int kt = 0; kt < 4; ++kt) {
            const float* wp = Whh + j * 64 + kt * 16 + 8 * hi;
            float4 u0 = *(const float4*)wp;
            float4 u1 = *(const float4*)(wp + 4);
            af[g][kt] = f16x8{(_Float16)(sc * u0.x), (_Float16)(sc * u0.y),
                              (_Float16)(sc * u0.z), (_Float16)(sc * u0.w),
                              (_Float16)(sc * u1.x), (_Float16)(sc * u1.y),
                              (_Float16)(sc * u1.z), (_Float16)(sc * u1.w)};
        }
        float v[8];
        #pragma unroll
        for (int e = 0; e < 5; ++e) v[e] = sc * Wih[j * Fc + e];
        v[5] = sc * (bih[j] + bhh[j]); v[6] = 0.f; v[7] = 0.f;
        #pragma unroll
        for (int e = 0; e < 8; ++e) {
            float z = hi ? 0.f : v[e];
            af[g][4][e] = (_Float16)z;
        }
    }

    // attention weights for owned units u = 32w + 8a2 + 4hi + p
    float aw_own[16];
    #pragma unroll
    for (int a2 = 0; a2 < 4; ++a2)
        #pragma unroll
        for (int p = 0; p < 4; ++p)
            aw_own[a2 * 4 + p] = attn_w[32 * w + 8 * a2 + 4 * hi + p];
    const float ab = attn_b[0];

    float hcur[16], cst[16], oacc[16];
    #pragma unroll
    for (int i = 0; i < 16; ++i) { hcur[i] = 0.f; cst[i] = 0.f; oacc[i] = 0.f; }
    float lsum = 0.f;

    f32x16 zero16 = {0,0,0,0,0,0,0,0,0,0,0,0,0,0,0,0};
    const int xrow = m * XP;
    const int swz  = m & 15;                    // chunk XOR swizzle
    __syncthreads();

    // ---- initial B fragments from hb[0] (zeros) + x(0) ----
    f16x8 bf[5];
    #pragma unroll
    for (int kt = 0; kt < 4; ++kt) {
        f16x4 lo = *(const f16x4*)&hbp[m * 64 + ((4 * kt + 2 * hi)     ^ swz) * 4];
        f16x4 hh = *(const f16x4*)&hbp[m * 64 + ((4 * kt + 2 * hi + 1) ^ swz) * 4];
        bf[kt] = f16x8{lo[0], lo[1], lo[2], lo[3], hh[0], hh[1], hh[2], hh[3]};
    }
    {
        #pragma unroll
        for (int e = 0; e < 8; ++e) bf[4][e] = (_Float16)0.f;
        if (!hi) {
            #pragma unroll
            for (int e = 0; e < 5; ++e) bf[4][e] = xs[xrow + e];
            bf[4][5] = (_Float16)1.f;
        }
    }

    #pragma unroll 1
    for (int t = 0; t < Tc; ++t) {
        // ---- gates: 4 gate tiles x 5 k-tiles ----
        f32x16 acc[4];
        #pragma unroll
        for (int g = 0; g < 4; ++g) {
            acc[g] = __builtin_amdgcn_mfma_f32_32x32x16_f16(af[g][0], bf[0], zero16, 0, 0, 0);
            #pragma unroll
            for (int kt = 1; kt < 5; ++kt)
                acc[g] = __builtin_amdgcn_mfma_f32_32x32x16_f16(af[g][kt], bf[kt], acc[g], 0, 0, 0);
        }
        // ---- cell update: 5 exp2 + 2 rcp per unit (weights pre-scaled) ----
        float attnp = 0.f;
        #pragma unroll
        for (int r = 0; r < 16; ++r) {
            float ei = exp2_fast(acc[0][r]);        // e^{-i}
            float ef = exp2_fast(acc[1][r]);        // e^{-f}
            float Eg = exp2_fast(acc[2][r]);        // e^{2g}
            float eo = exp2_fast(acc[3][r]);        // e^{-o}
            float u  = 1.f + ei;
            float v  = 1.f + ef;
            float wq = Eg + 1.f;
            float z  = Eg - 1.f;
            float t1 = u * wq;
            float num = fmaf(cst[r], t1, z * v);
            float cn = num * fast_rcp(t1 * v);
            cst[r] = cn;
            float E2 = exp2_fast(2.f * L2E * cn);   // e^{2c}
            float hv = (E2 - 1.f) * fast_rcp((E2 + 1.f) * (1.f + eo));
            hcur[r] = hv;
            attnp = fmaf(hv, aw_own[r], attnp);
        }
        // ---- publish h (fp16, swizzled chunks) + attention partial ----
        _Float16* hw = hbp + ((t + 1) & 1) * 2048;
        #pragma unroll
        for (int a2 = 0; a2 < 4; ++a2) {
            f16x4 pk = {(_Float16)hcur[4 * a2 + 0], (_Float16)hcur[4 * a2 + 1],
                        (_Float16)hcur[4 * a2 + 2], (_Float16)hcur[4 * a2 + 3]};
            *(f16x4*)&hw[m * 64 + ((8 * w + 2 * a2 + hi) ^ swz) * 4] = pk;
        }
        attnp += __shfl_xor(attnp, 32);
        if (!hi) ap[w * 32 + m] = attnp;
        __syncthreads();
        // ---- score + online accumulation (both waves identical) ----
        float sc = tanh_fast(ap[m] + ap[32 + m] + ab);
        float ew = __expf(sc);
        lsum += ew;
        #pragma unroll
        for (int i = 0; i < 16; ++i) oacc[i] = fmaf(ew, hcur[i], oacc[i]);
        // ---- build next B fragments ----
        if (t != Tc - 1) {
            const _Float16* hr = hbp + ((t + 1) & 1) * 2048;
            #pragma unroll
            for (int kt = 0; kt < 4; ++kt) {
                f16x4 lo = *(const f16x4*)&hr[m * 64 + ((4 * kt + 2 * hi)     ^ swz) * 4];
                f16x4 hh = *(const f16x4*)&hr[m * 64 + ((4 * kt + 2 * hi + 1) ^ swz) * 4];
                bf[kt] = f16x8{lo[0], lo[1], lo[2], lo[3], hh[0], hh[1], hh[2], hh[3]};
            }
            if (!hi) {
                #pragma unroll
                for (int e = 0; e < 5; ++e) bf[4][e] = xs[xrow + (t + 1) * Fc + e];
                bf[4][5] = (_Float16)1.f;
            }
        }
    }

    // ---- epilogue: es[m][u] = oacc/lsum, then E16 + ET ----
    __syncthreads();                    // xs reads done before aliasing
    const float li = fast_rcp(lsum);
    #pragma unroll
    for (int r = 0; r < 16; ++r) {
        int u = 32 * w + 8 * (r >> 2) + 4 * hi + (r & 3);
        es[m * 65 + u] = oacc[r] * li;
    }
    __syncthreads();

    uint* E16u = (uint*)E16 + (size_t)blockIdx.x * 32 * 32;
    for (int idx = tid; idx < 32 * 32; idx += 128) {
        int mm = idx >> 5, hp = idx & 31;
        union { _Float16 h2[2]; uint u; } cv;
        cv.h2[0] = (_Float16)es[mm * 65 + 2 * hp];
        cv.h2[1] = (_Float16)es[mm * 65 + 2 * hp + 1];
        E16u[idx] = cv.u;
    }
    const int bb_ = blockIdx.x >> 5, n0d = (blockIdx.x & 31) * 16;
    uint* ETu = (uint*)ET;
    for (int idx = tid; idx < 64 * 16; idx += 128) {
        int h = idx >> 4, c = idx & 15;
        union { _Float16 h2[2]; uint u; } cv;
        cv.h2[0] = (_Float16)es[(2 * c) * 65 + h];
        cv.h2[1] = (_Float16)es[(2 * c + 1) * 65 + h];
        ETu[((size_t)bb_ * 64 + h) * 512 + n0d + c] = cv.u;
    }
}

// ---------------- Kernel 3: MFMA GNN message pass + prediction head ---------
__global__ __launch_bounds__(256, 2) void gnn_pred_kernel(
    const _Float16* __restrict__ E16,  // [B*N, H]
    const _Float16* __restrict__ ET,   // [B][H][N]
    const _Float16* __restrict__ coefQH,// [N/4][N][4] fp16
    const float* __restrict__ degP,    // [32][N]
    const float* __restrict__ pred_w,  // [2H]
    const float* __restrict__ pred_b,  // [1]
    float* __restrict__ preds)         // [B*N]
{
    __shared__ __align__(16) _Float16 tiles[2][4][64 * 64];  // 64 KB exactly
    const int tid  = threadIdx.x;
    const int w    = tid >> 6;
    const int lane = tid & 63;
    const int l31  = lane & 31;
    const int hi   = lane >> 5;
    const int it   = blockIdx.x >> 5;           // it-major (XCD locality)
    const int b    = blockIdx.x & 31;

    _Float16* EA = &tiles[0][w][0];
    _Float16* EB = &tiles[1][w][0];
    const f16x4* cq = (const f16x4*)coefQH;

    f16x8 eb[2][4];
    #pragma unroll
    for (int ni = 0; ni < 2; ++ni)
        #pragma unroll
        for (int kt = 0; kt < 4; ++kt)
            eb[ni][kt] = *(const f16x8*)(E16 +
                ((size_t)(b * 1024 + it * 64 + ni * 32 + l31) * 64 + 16 * kt + 8 * hi));

    f32x16 zero16 = {0,0,0,0,0,0,0,0,0,0,0,0,0,0,0,0};
    f32x16 oacc[2][2];
    #pragma unroll
    for (int mi = 0; mi < 2; ++mi)
        #pragma unroll
        for (int nh = 0; nh < 2; ++nh) oacc[mi][nh] = zero16;

    #pragma unroll 1
    for (int s = 0; s < 4; ++s) {
        const int jt = w * 4 + s;
        const _Float16* srcA = E16 + (size_t)(b * 1024 + jt * 64) * 64;
        const _Float16* srcB = ET + (size_t)b * 64 * 1024 + jt * 64;
        #pragma unroll
        for (int q = 0; q < 8; ++q) {
            int f = q * 64 + lane, r = f >> 3, c = f & 7;
            uint4 va = *(const uint4*)(srcA + r * 64 + c * 8);
            *(uint4*)(EA + r * 64 + ((c ^ (r & 7)) * 8)) = va;
            uint4 vb = *(const uint4*)(srcB + r * 1024 + c * 8);
            *(uint4*)(EB + r * 64 + ((c ^ (r & 7)) * 8)) = vb;
        }
        #pragma unroll 1
        for (int mj = 0; mj < 2; ++mj) {
            f16x8 af[4];
            #pragma unroll
            for (int kt = 0; kt < 4; ++kt)
                af[kt] = *(const f16x8*)(EA + (mj * 32 + l31) * 64 +
                                         (((2 * kt + hi) ^ (l31 & 7)) * 8));
            #pragma unroll
            for (int mi = 0; mi < 2; ++mi) {
                // S' = Ej . Ei^T  (16 regs live)
                f32x16 a = __builtin_amdgcn_mfma_f32_32x32x16_f16(af[0], eb[mi][0], zero16, 0, 0, 0);
                #pragma unroll
                for (int kt = 1; kt < 4; ++kt)
                    a = __builtin_amdgcn_mfma_f32_32x32x16_f16(af[kt], eb[mi][kt], a, 0, 0, 0);
                // P = S' * coef (fp16 coef, 8B per lane)
                #pragma unroll
                for (int rg = 0; rg < 4; ++rg) {
                    int j0 = jt * 64 + mj * 32 + 8 * rg + 4 * hi;
                    f16x4 cfh = cq[(size_t)(j0 >> 2) * 1024 + it * 64 + mi * 32 + l31];
                    a[4 * rg + 0] *= (float)cfh[0]; a[4 * rg + 1] *= (float)cfh[1];
                    a[4 * rg + 2] *= (float)cfh[2]; a[4 * rg + 3] *= (float)cfh[3];
                }
                // pack C-layout -> fp16 A-frags via lane^32 swap
                f16x8 pa[2];
                #pragma unroll
                for (int kk = 0; kk < 2; ++kk) {
                    const int rg = 2 * kk;
                    #pragma unroll
                    for (int c4 = 0; c4 < 4; ++c4) {
                        float own_lo = a[rg * 4 + c4];
                        float own_hi = a[(rg + 1) * 4 + c4];
                        float send = hi ? own_lo : own_hi;
                        float recv = __shfl_xor(send, 32);
                        float lo = hi ? recv : own_lo;
                        float hv = hi ? own_hi : recv;
                        pa[kk][c4]     = (_Float16)lo;
                        pa[kk][4 + c4] = (_Float16)hv;
                    }
                }
                // O += P . Ej
                #pragma unroll
                for (int nh = 0; nh < 2; ++nh)
                    #pragma unroll
                    for (int kk = 0; kk < 2; ++kk) {
                        const int ktj = 2 * mj + kk;
                        f16x8 bb = *(const f16x8*)(EB + (nh * 32 + l31) * 64 +
                                                   (((2 * ktj + hi) ^ (l31 & 7)) * 8));
                        oacc[mi][nh] = __builtin_amdgcn_mfma_f32_32x32x16_f16(
                            pa[kk], bb, oacc[mi][nh], 0, 0, 0);
                    }
            }
        }
    }

    // ---- epilogue: per-wave O.pwh partials -> LDS (aliases dead EA tile) ---
    float* pacc = (float*)&tiles[0][w][0];      // 64 floats, wave-private
    const float pwh0 = pred_w[64 + l31];
    const float pwh1 = pred_w[96 + l31];
    #pragma unroll
    for (int mi = 0; mi < 2; ++mi)
        #pragma unroll
        for (int r = 0; r < 16; ++r) {
            float v = oacc[mi][0][r] * pwh0 + oacc[mi][1][r] * pwh1;
            v += __shfl_xor(v, 1);  v += __shfl_xor(v, 2);  v += __shfl_xor(v, 4);
            v += __shfl_xor(v, 8);  v += __shfl_xor(v, 16);
            int i_loc = mi * 32 + 8 * (r >> 2) + (r & 3) + 4 * hi;
            if (l31 == 0) pacc[i_loc] = v;
        }
    __syncthreads();
    if (w == 0) {
        const float pb0 = pred_b[0];
        #pragma unroll
        for (int ni = 0; ni < 2; ++ni) {
            float dot = 0.f;
            #pragma unroll
            for (int kt = 0; kt < 4; ++kt)
                #pragma unroll
                for (int e = 0; e < 8; ++e)
                    dot = fmaf((float)eb[ni][kt][e], pred_w[16 * kt + 8 * hi + e], dot);
            dot += __shfl_xor(dot, 32);
            if (hi == 0) {
                int i_loc = ni * 32 + l31;
                int gi = it * 64 + i_loc;
                float osum = ((float*)&tiles[0][0][0])[i_loc] +
                             ((float*)&tiles[0][1][0])[i_loc] +
                             ((float*)&tiles[0][2][0])[i_loc] +
                             ((float*)&tiles[0][3][0])[i_loc];
                float dsum = 0.f;
                #pragma unroll
                for (int jj = 0; jj < 32; ++jj) dsum += degP[jj * 1024 + gi];
                preds[b * 1024 + gi] = dot + osum * fast_rcp(dsum) + pb0;
            }
        }
    }
}

extern "C" void kernel_launch(void* const* d_in, const int* in_sizes, int n_in,
                              void* d_out, int out_size, void* d_ws, size_t ws_size,
                              hipStream_t stream) {
    const float* x      = (const float*)d_in[0];
    const float* A      = (const float*)d_in[1];
    const float* Wih    = (const float*)d_in[2];
    const float* Whh    = (const float*)d_in[3];
    const float* bih    = (const float*)d_in[4];
    const float* bhh    = (const float*)d_in[5];
    const float* attn_w = (const float*)d_in[6];
    const float* attn_b = (const float*)d_in[7];
    const float* gnn_w  = (const float*)d_in[8];
    const float* gnn_b  = (const float*)d_in[9];
    const float* pred_w = (const float*)d_in[10];
    const float* pred_b = (const float*)d_in[11];
    float* preds = (float*)d_out;

    // ws: E16 (4MB) | ET (4MB) | coefQH (2MB) | degP (128KB)
    _Float16* E16    = (_Float16*)d_ws;
    _Float16* ET     = E16 + (size_t)BNc * Hc;
    _Float16* coefQH = ET + (size_t)BNc * Hc;
    float* degP      = (float*)(coefQH + (size_t)Nc * Nc);

    lstm_coefq_kernel<<<2048, 128, 0, stream>>>(x, Wih, Whh, bih, bhh,
                                                attn_w, attn_b, A, gnn_w, gnn_b,
                                                E16, ET, coefQH, degP);
    gnn_pred_kernel<<<Bc * (Nc / 64), 256, 0, stream>>>(E16, ET, coefQH, degP,
                                                        pred_w, pred_b, preds);
}

// Round 14
// 211.840 us; speedup vs baseline: 2.3204x; 2.3204x over previous
//
#include <hip/hip_runtime.h>

// Problem constants (B,N,T,F,H,R) = (32,1024,32,5,64,5)
constexpr int Bc = 32, Nc = 1024, Tc = 32, Fc = 5, Hc = 64;
constexpr int BNc = Bc * Nc;   // 32768 sequences

#define DEVFN __device__ __forceinline__

typedef _Float16 f16x8 __attribute__((ext_vector_type(8)));
typedef _Float16 f16x4 __attribute__((ext_vector_type(4)));
typedef float    f32x16 __attribute__((ext_vector_type(16)));

DEVFN float fast_rcp(float x) { return __builtin_amdgcn_rcpf(x); }
DEVFN float tanh_fast(float x) { return 1.f - 2.f * fast_rcp(__expf(2.f * x) + 1.f); }

#if __has_builtin(__builtin_amdgcn_exp2f)
DEVFN float exp2_fast(float x) { return __builtin_amdgcn_exp2f(x); }
#else
DEVFN float exp2_fast(float x) { return exp2f(x); }
#endif

// ------------- Fused kernel: LSTM+attention (blocks 0..1023) ----------------
//                + edge-coefficient phase (blocks 1024..2047)
// R12 exact revert (best measured 211.99 µs). launch_bounds(128,2): the real
// register footprint is ~188 (124 VGPR + 64 AGPR acc on the unified file), so
// 2 waves/SIMD is the occupancy ceiling — bounds >=3 forces spills (R13:
// VGPR cut to 64, ~1 GB spill traffic, 419 µs).
__global__ __launch_bounds__(128, 2) void lstm_coefq_kernel(
    const float* __restrict__ x,      // [BN, T, F]
    const float* __restrict__ Wih,    // [4H, F]
    const float* __restrict__ Whh,    // [4H, H]
    const float* __restrict__ bih,    // [4H]
    const float* __restrict__ bhh,    // [4H]
    const float* __restrict__ attn_w, // [H]
    const float* __restrict__ attn_b, // [1]
    const float* __restrict__ A,      // [N, N, R]
    const float* __restrict__ gnn_w,  // [R]
    const float* __restrict__ gnn_b,  // [1]
    _Float16* __restrict__ E16,       // [B*N, H] fp16 row-major
    _Float16* __restrict__ ET,        // [B][H][N] fp16 transposed
    _Float16* __restrict__ coefQH,    // [N/4][N][4] fp16
    float* __restrict__ degP)         // [32][N] partial counts
{
    // LDS overlay: lstm uses 18.9 KB (xs 10496 | hb 8192 | ap 256);
    // coefq uses 21.0 KB (as 20736 | dcnt 256). Max = 20992 B.
    __shared__ __align__(16) char smem[20992];

    const int tid  = threadIdx.x;

    if (blockIdx.x >= 1024) {
        // =================== coefq phase (128 threads) ======================
        constexpr int CP = 162;                 // float pitch
        float* as   = (float*)smem;             // [32][162]
        float* dcnt = (float*)(smem + 20736);   // [2][32]
        const int cb = blockIdx.x - 1024;
        const int it = cb >> 5, jt = cb & 31;
        const int w    = tid >> 6;
        const int lane = tid & 63;

        float gw[5];
        #pragma unroll
        for (int f = 0; f < 5; ++f) gw[f] = gnn_w[f];
        const float gb = gnn_b[0];

        // stage 32 rows x 160 floats (coalesced float2)
        const float* src = A + ((size_t)it * 32 * 1024 + jt * 32) * 5;
        #pragma unroll
        for (int k = 0; k < 20; ++k) {
            int idx = tid + k * 128;            // 0..2559
            int row = idx / 80, c2 = idx - row * 80;
            *(float2*)&as[row * CP + c2 * 2] =
                *(const float2*)(src + (size_t)row * 5120 + c2 * 2);
        }
        __syncthreads();

        // thread (q2 = tid>>5, i_loc = tid&31) handles quads 2q2, 2q2+1
        const int q2 = tid >> 5, i_loc = tid & 31;
        float cnt = 0.f;
        #pragma unroll
        for (int gg2 = 0; gg2 < 2; ++gg2) {
            const int gg = 2 * q2 + gg2;
            float cf[4];
            #pragma unroll
            for (int q = 0; q < 4; ++q) {
                const float* ap_ = &as[i_loc * CP + (gg * 4 + q) * 5];
                float s = 0.f, d = gb;
                #pragma unroll
                for (int f = 0; f < 5; ++f) { float vv = ap_[f]; s += vv; d = fmaf(vv, gw[f], d); }
                cf[q] = (s > 0.f) ? (d >= 0.f ? d : 0.2f * d) : 0.f;
                cnt += (s > 0.f) ? 1.f : 0.f;
            }
            ((f16x4*)coefQH)[(size_t)(jt * 8 + gg) * 1024 + it * 32 + i_loc] =
                f16x4{(_Float16)cf[0], (_Float16)cf[1], (_Float16)cf[2], (_Float16)cf[3]};
        }
        // degree: combine q2 pairs within wave, then across waves via LDS
        cnt += __shfl_xor(cnt, 32);
        if (lane < 32) dcnt[w * 32 + i_loc] = cnt;
        __syncthreads();
        if (tid < 32)
            degP[jt * 1024 + it * 32 + tid] = dcnt[tid] + dcnt[32 + tid];
        return;
    }

    // ======================= LSTM + attention phase =========================
    constexpr int XP = 164;                     // x pitch (halves)
    _Float16* xs = (_Float16*)smem;             // [32][164]; aliased w/ es
    _Float16* hbp = (_Float16*)(smem + 10496);  // [2][32*64]
    float*    ap  = (float*)(smem + 10496 + 8192); // [2][32]
    float*    es  = (float*)xs;                 // [32][65] epilogue bounce

    const int w    = tid >> 6;                  // wave id (0,1)
    const int lane = tid & 63;
    const int m    = lane & 31;                 // seq column
    const int hi   = lane >> 5;

    // ---- stage x (fp32 -> fp16 LDS) ----
    const float* xg = x + (size_t)blockIdx.x * 32 * Tc * Fc;
    for (int i = tid; i < 32 * 160; i += 128) {
        int mm = i / 160, o = i - mm * 160;
        xs[mm * XP + o] = (_Float16)xg[i];
    }
    // zero h buffer 0
    for (int i = tid; i < 1024; i += 128) ((uint*)hbp)[i] = 0u;

    // per-gate exp2 folding scales (gate order i,f,g,o)
    constexpr float L2E = 1.4426950408889634f;
    const float gsc[4] = {-L2E, -L2E, 2.f * L2E, -L2E};

    // ---- preload A fragments: af[g][kt], jt = 2g+w, row j = 32*jt + m ----
    f16x8 af[4][5];
    #pragma unroll
    for (int g = 0; g < 4; ++g) {
        const int j = 32 * (2 * g + w) + m;     // = 64g + 32w + m
        const float sc = gsc[g];
        #pragma unroll
        for (int kt = 0; kt < 4; ++kt) {
            const float* wp = Whh + j * 64 + kt * 16 + 8 * hi;
            float4 u0 = *(const float4*)wp;
            float4 u1 = *(const float4*)(wp + 4);
            af[g][kt] = f16x8{(_Float16)(sc * u0.x), (_Float16)(sc * u0.y),
                              (_Float16)(sc * u0.z), (_Float16)(sc * u0.w),
                              (_Float16)(sc * u1.x), (_Float16)(sc * u1.y),
                              (_Float16)(sc * u1.z), (_Float16)(sc * u1.w)};
        }
        float v[8];
        #pragma unroll
        for (int e = 0; e < 5; ++e) v[e] = sc * Wih[j * Fc + e];
        v[5] = sc * (bih[j] + bhh[j]); v[6] = 0.f; v[7] = 0.f;
        #pragma unroll
        for (int e = 0; e < 8; ++e) {
            float z = hi ? 0.f : v[e];
            af[g][4][e] = (_Float16)z;
        }
    }

    // attention weights for owned units u = 32w + 8a2 + 4hi + p
    float aw_own[16];
    #pragma unroll
    for (int a2 = 0; a2 < 4; ++a2)
        #pragma unroll
        for (int p = 0; p < 4; ++p)
            aw_own[a2 * 4 + p] = attn_w[32 * w + 8 * a2 + 4 * hi + p];
    const float ab = attn_b[0];

    float hcur[16], cst[16], oacc[16];
    #pragma unroll
    for (int i = 0; i < 16; ++i) { hcur[i] = 0.f; cst[i] = 0.f; oacc[i] = 0.f; }
    float lsum = 0.f;

    f32x16 zero16 = {0,0,0,0,0,0,0,0,0,0,0,0,0,0,0,0};
    const int xrow = m * XP;
    const int swz  = m & 15;                    // chunk XOR swizzle
    __syncthreads();

    // ---- initial B fragments from hb[0] (zeros) + x(0) ----
    f16x8 bf[5];
    #pragma unroll
    for (int kt = 0; kt < 4; ++kt) {
        f16x4 lo = *(const f16x4*)&hbp[m * 64 + ((4 * kt + 2 * hi)     ^ swz) * 4];
        f16x4 hh = *(const f16x4*)&hbp[m * 64 + ((4 * kt + 2 * hi + 1) ^ swz) * 4];
        bf[kt] = f16x8{lo[0], lo[1], lo[2], lo[3], hh[0], hh[1], hh[2], hh[3]};
    }
    {
        #pragma unroll
        for (int e = 0; e < 8; ++e) bf[4][e] = (_Float16)0.f;
        if (!hi) {
            #pragma unroll
            for (int e = 0; e < 5; ++e) bf[4][e] = xs[xrow + e];
            bf[4][5] = (_Float16)1.f;
        }
    }

    #pragma unroll 1
    for (int t = 0; t < Tc; ++t) {
        // ---- gates: 4 gate tiles x 5 k-tiles ----
        f32x16 acc[4];
        #pragma unroll
        for (int g = 0; g < 4; ++g) {
            acc[g] = __builtin_amdgcn_mfma_f32_32x32x16_f16(af[g][0], bf[0], zero16, 0, 0, 0);
            #pragma unroll
            for (int kt = 1; kt < 5; ++kt)
                acc[g] = __builtin_amdgcn_mfma_f32_32x32x16_f16(af[g][kt], bf[kt], acc[g], 0, 0, 0);
        }
        // ---- cell update: 5 exp2 + 2 rcp per unit (weights pre-scaled) ----
        float attnp = 0.f;
        #pragma unroll
        for (int r = 0; r < 16; ++r) {
            float ei = exp2_fast(acc[0][r]);        // e^{-i}
            float ef = exp2_fast(acc[1][r]);        // e^{-f}
            float Eg = exp2_fast(acc[2][r]);        // e^{2g}
            float eo = exp2_fast(acc[3][r]);        // e^{-o}
            float u  = 1.f + ei;
            float v  = 1.f + ef;
            float wq = Eg + 1.f;
            float z  = Eg - 1.f;
            float t1 = u * wq;
            float num = fmaf(cst[r], t1, z * v);
            float cn = num * fast_rcp(t1 * v);
            cst[r] = cn;
            float E2 = exp2_fast(2.f * L2E * cn);   // e^{2c}
            float hv = (E2 - 1.f) * fast_rcp((E2 + 1.f) * (1.f + eo));
            hcur[r] = hv;
            attnp = fmaf(hv, aw_own[r], attnp);
        }
        // ---- publish h (fp16, swizzled chunks) + attention partial ----
        _Float16* hw = hbp + ((t + 1) & 1) * 2048;
        #pragma unroll
        for (int a2 = 0; a2 < 4; ++a2) {
            f16x4 pk = {(_Float16)hcur[4 * a2 + 0], (_Float16)hcur[4 * a2 + 1],
                        (_Float16)hcur[4 * a2 + 2], (_Float16)hcur[4 * a2 + 3]};
            *(f16x4*)&hw[m * 64 + ((8 * w + 2 * a2 + hi) ^ swz) * 4] = pk;
        }
        attnp += __shfl_xor(attnp, 32);
        if (!hi) ap[w * 32 + m] = attnp;
        __syncthreads();
        // ---- score + online accumulation (both waves identical) ----
        float sc = tanh_fast(ap[m] + ap[32 + m] + ab);
        float ew = __expf(sc);
        lsum += ew;
        #pragma unroll
        for (int i = 0; i < 16; ++i) oacc[i] = fmaf(ew, hcur[i], oacc[i]);
        // ---- build next B fragments ----
        if (t != Tc - 1) {
            const _Float16* hr = hbp + ((t + 1) & 1) * 2048;
            #pragma unroll
            for (int kt = 0; kt < 4; ++kt) {
                f16x4 lo = *(const f16x4*)&hr[m * 64 + ((4 * kt + 2 * hi)     ^ swz) * 4];
                f16x4 hh = *(const f16x4*)&hr[m * 64 + ((4 * kt + 2 * hi + 1) ^ swz) * 4];
                bf[kt] = f16x8{lo[0], lo[1], lo[2], lo[3], hh[0], hh[1], hh[2], hh[3]};
            }
            if (!hi) {
                #pragma unroll
                for (int e = 0; e < 5; ++e) bf[4][e] = xs[xrow + (t + 1) * Fc + e];
                bf[4][5] = (_Float16)1.f;
            }
        }
    }

    // ---- epilogue: es[m][u] = oacc/lsum, then E16 + ET ----
    __syncthreads();                    // xs reads done before aliasing
    const float li = fast_rcp(lsum);
    #pragma unroll
    for (int r = 0; r < 16; ++r) {
        int u = 32 * w + 8 * (r >> 2) + 4 * hi + (r & 3);
        es[m * 65 + u] = oacc[r] * li;
    }
    __syncthreads();

    uint* E16u = (uint*)E16 + (size_t)blockIdx.x * 32 * 32;
    for (int idx = tid; idx < 32 * 32; idx += 128) {
        int mm = idx >> 5, hp = idx & 31;
        union { _Float16 h2[2]; uint u; } cv;
        cv.h2[0] = (_Float16)es[mm * 65 + 2 * hp];
        cv.h2[1] = (_Float16)es[mm * 65 + 2 * hp + 1];
        E16u[idx] = cv.u;
    }
    const int bb_ = blockIdx.x >> 5, n0d = (blockIdx.x & 31) * 16;
    uint* ETu = (uint*)ET;
    for (int idx = tid; idx < 64 * 16; idx += 128) {
        int h = idx >> 4, c = idx & 15;
        union { _Float16 h2[2]; uint u; } cv;
        cv.h2[0] = (_Float16)es[(2 * c) * 65 + h];
        cv.h2[1] = (_Float16)es[(2 * c + 1) * 65 + h];
        ETu[((size_t)bb_ * 64 + h) * 512 + n0d + c] = cv.u;
    }
}

// ---------------- Kernel 3: MFMA GNN message pass + prediction head ---------
__global__ __launch_bounds__(256, 2) void gnn_pred_kernel(
    const _Float16* __restrict__ E16,  // [B*N, H]
    const _Float16* __restrict__ ET,   // [B][H][N]
    const _Float16* __restrict__ coefQH,// [N/4][N][4] fp16
    const float* __restrict__ degP,    // [32][N]
    const float* __restrict__ pred_w,  // [2H]
    const float* __restrict__ pred_b,  // [1]
    float* __restrict__ preds)         // [B*N]
{
    __shared__ __align__(16) _Float16 tiles[2][4][64 * 64];  // 64 KB exactly
    const int tid  = threadIdx.x;
    const int w    = tid >> 6;
    const int lane = tid & 63;
    const int l31  = lane & 31;
    const int hi   = lane >> 5;
    const int it   = blockIdx.x >> 5;           // it-major (XCD locality)
    const int b    = blockIdx.x & 31;

    _Float16* EA = &tiles[0][w][0];
    _Float16* EB = &tiles[1][w][0];
    const f16x4* cq = (const f16x4*)coefQH;

    f16x8 eb[2][4];
    #pragma unroll
    for (int ni = 0; ni < 2; ++ni)
        #pragma unroll
        for (int kt = 0; kt < 4; ++kt)
            eb[ni][kt] = *(const f16x8*)(E16 +
                ((size_t)(b * 1024 + it * 64 + ni * 32 + l31) * 64 + 16 * kt + 8 * hi));

    f32x16 zero16 = {0,0,0,0,0,0,0,0,0,0,0,0,0,0,0,0};
    f32x16 oacc[2][2];
    #pragma unroll
    for (int mi = 0; mi < 2; ++mi)
        #pragma unroll
        for (int nh = 0; nh < 2; ++nh) oacc[mi][nh] = zero16;

    #pragma unroll 1
    for (int s = 0; s < 4; ++s) {
        const int jt = w * 4 + s;
        const _Float16* srcA = E16 + (size_t)(b * 1024 + jt * 64) * 64;
        const _Float16* srcB = ET + (size_t)b * 64 * 1024 + jt * 64;
        #pragma unroll
        for (int q = 0; q < 8; ++q) {
            int f = q * 64 + lane, r = f >> 3, c = f & 7;
            uint4 va = *(const uint4*)(srcA + r * 64 + c * 8);
            *(uint4*)(EA + r * 64 + ((c ^ (r & 7)) * 8)) = va;
            uint4 vb = *(const uint4*)(srcB + r * 1024 + c * 8);
            *(uint4*)(EB + r * 64 + ((c ^ (r & 7)) * 8)) = vb;
        }
        #pragma unroll 1
        for (int mj = 0; mj < 2; ++mj) {
            f16x8 af[4];
            #pragma unroll
            for (int kt = 0; kt < 4; ++kt)
                af[kt] = *(const f16x8*)(EA + (mj * 32 + l31) * 64 +
                                         (((2 * kt + hi) ^ (l31 & 7)) * 8));
            #pragma unroll
            for (int mi = 0; mi < 2; ++mi) {
                // S' = Ej . Ei^T  (16 regs live)
                f32x16 a = __builtin_amdgcn_mfma_f32_32x32x16_f16(af[0], eb[mi][0], zero16, 0, 0, 0);
                #pragma unroll
                for (int kt = 1; kt < 4; ++kt)
                    a = __builtin_amdgcn_mfma_f32_32x32x16_f16(af[kt], eb[mi][kt], a, 0, 0, 0);
                // P = S' * coef (fp16 coef, 8B per lane)
                #pragma unroll
                for (int rg = 0; rg < 4; ++rg) {
                    int j0 = jt * 64 + mj * 32 + 8 * rg + 4 * hi;
                    f16x4 cfh = cq[(size_t)(j0 >> 2) * 1024 + it * 64 + mi * 32 + l31];
                    a[4 * rg + 0] *= (float)cfh[0]; a[4 * rg + 1] *= (float)cfh[1];
                    a[4 * rg + 2] *= (float)cfh[2]; a[4 * rg + 3] *= (float)cfh[3];
                }
                // pack C-layout -> fp16 A-frags via lane^32 swap
                f16x8 pa[2];
                #pragma unroll
                for (int kk = 0; kk < 2; ++kk) {
                    const int rg = 2 * kk;
                    #pragma unroll
                    for (int c4 = 0; c4 < 4; ++c4) {
                        float own_lo = a[rg * 4 + c4];
                        float own_hi = a[(rg + 1) * 4 + c4];
                        float send = hi ? own_lo : own_hi;
                        float recv = __shfl_xor(send, 32);
                        float lo = hi ? recv : own_lo;
                        float hv = hi ? own_hi : recv;
                        pa[kk][c4]     = (_Float16)lo;
                        pa[kk][4 + c4] = (_Float16)hv;
                    }
                }
                // O += P . Ej
                #pragma unroll
                for (int nh = 0; nh < 2; ++nh)
                    #pragma unroll
                    for (int kk = 0; kk < 2; ++kk) {
                        const int ktj = 2 * mj + kk;
                        f16x8 bb = *(const f16x8*)(EB + (nh * 32 + l31) * 64 +
                                                   (((2 * ktj + hi) ^ (l31 & 7)) * 8));
                        oacc[mi][nh] = __builtin_amdgcn_mfma_f32_32x32x16_f16(
                            pa[kk], bb, oacc[mi][nh], 0, 0, 0);
                    }
            }
        }
    }

    // ---- epilogue: per-wave O.pwh partials -> LDS (aliases dead EA tile) ---
    float* pacc = (float*)&tiles[0][w][0];      // 64 floats, wave-private
    const float pwh0 = pred_w[64 + l31];
    const float pwh1 = pred_w[96 + l31];
    #pragma unroll
    for (int mi = 0; mi < 2; ++mi)
        #pragma unroll
        for (int r = 0; r < 16; ++r) {
            float v = oacc[mi][0][r] * pwh0 + oacc[mi][1][r] * pwh1;
            v += __shfl_xor(v, 1);  v += __shfl_xor(v, 2);  v += __shfl_xor(v, 4);
            v += __shfl_xor(v, 8);  v += __shfl_xor(v, 16);
            int i_loc = mi * 32 + 8 * (r >> 2) + (r & 3) + 4 * hi;
            if (l31 == 0) pacc[i_loc] = v;
        }
    __syncthreads();
    if (w == 0) {
        const float pb0 = pred_b[0];
        #pragma unroll
        for (int ni = 0; ni < 2; ++ni) {
            float dot = 0.f;
            #pragma unroll
            for (int kt = 0; kt < 4; ++kt)
                #pragma unroll
                for (int e = 0; e < 8; ++e)
                    dot = fmaf((float)eb[ni][kt][e], pred_w[16 * kt + 8 * hi + e], dot);
            dot += __shfl_xor(dot, 32);
            if (hi == 0) {
                int i_loc = ni * 32 + l31;
                int gi = it * 64 + i_loc;
                float osum = ((float*)&tiles[0][0][0])[i_loc] +
                             ((float*)&tiles[0][1][0])[i_loc] +
                             ((float*)&tiles[0][2][0])[i_loc] +
                             ((float*)&tiles[0][3][0])[i_loc];
                float dsum = 0.f;
                #pragma unroll
                for (int jj = 0; jj < 32; ++jj) dsum += degP[jj * 1024 + gi];
                preds[b * 1024 + gi] = dot + osum * fast_rcp(dsum) + pb0;
            }
        }
    }
}

extern "C" void kernel_launch(void* const* d_in, const int* in_sizes, int n_in,
                              void* d_out, int out_size, void* d_ws, size_t ws_size,
                              hipStream_t stream) {
    const float* x      = (const float*)d_in[0];
    const float* A      = (const float*)d_in[1];
    const float* Wih    = (const float*)d_in[2];
    const float* Whh    = (const float*)d_in[3];
    const float* bih    = (const float*)d_in[4];
    const float* bhh    = (const float*)d_in[5];
    const float* attn_w = (const float*)d_in[6];
    const float* attn_b = (const float*)d_in[7];
    const float* gnn_w  = (const float*)d_in[8];
    const float* gnn_b  = (const float*)d_in[9];
    const float* pred_w = (const float*)d_in[10];
    const float* pred_b = (const float*)d_in[11];
    float* preds = (float*)d_out;

    // ws: E16 (4MB) | ET (4MB) | coefQH (2MB) | degP (128KB)
    _Float16* E16    = (_Float16*)d_ws;
    _Float16* ET     = E16 + (size_t)BNc * Hc;
    _Float16* coefQH = ET + (size_t)BNc * Hc;
    float* degP      = (float*)(coefQH + (size_t)Nc * Nc);

    lstm_coefq_kernel<<<2048, 128, 0, stream>>>(x, Wih, Whh, bih, bhh,
                                                attn_w, attn_b, A, gnn_w, gnn_b,
                                                E16, ET, coefQH, degP);
    gnn_pred_kernel<<<Bc * (Nc / 64), 256, 0, stream>>>(E16, ET, coefQH, degP,
                                                        pred_w, pred_b, preds);
}